// Round 13
// baseline (107.082 us; speedup 1.0000x reference)
//
#include <hip/hip_runtime.h>

// TopKActivation: out = relu(x) masked to the row-wise top-k of relu(x).
// [16384 x 4096] fp32, k=64. TWO rows per 256-thread block (grid 8192):
// both rows' loads issued up front; all barriers are LDS-only (no vmcnt
// drain), so row B's loads stay in flight through row A's select+emit.
//
// LESSON LEDGER:
//  R3:  persistent+prefetch+bar_lds -> 214us. CONFOUNDED: had NT stores.
//  R4:  launch_bounds(256,8) -> 302us (write amplification).
//  R5:  NT stores -> 523MB writes: partial-line HBM write amplification. POISON.
//  R6:  plain stores -> 127.5us.
//  R7:  coalesced interleaved layout -> 100.9us (was 4x transactions).
//  R8:  redundant all-wave select -> 112.5us (4x shared-pipe LDS traffic).
//  R9:  ballot compaction + tie fast-path -> 100.1us.
//  R11: zero-barrier wave-per-row -> 114.4us (VGPR pressure, serial ballots).
//  R12: 3-pass offset radix, 2 barriers -> 101.2us (flat: select isn't the gap).
//  R13 (this): hide select latency under the other row's loads via LDS-only
//       barriers. Plain stores, no persistence, same proven select as R12.
//
// Select: candidates > 1.5f ballot-compacted (as key-1.5bits, 24-bit) into 4
// per-wave 128-slot segments; wave 0 runs 3x8-bit MSB radix. Exact full-block
// fallback if any segment overflows, cnt<k, or any element >= 6.0. Tie
// ambiguity decided in-select (final-pass bin count); stable ranks (lowest
// column first, == XLA top_k) only on the rare ambiguous row.

constexpr int ROW_LEN = 4096;
constexpr int TPB     = 256;
constexpr int SEG     = 128;
constexpr unsigned int KPRE_BITS = 0x3FC00000u; // 1.5f
constexpr unsigned int KMAX_BITS = 0x40C00000u; // 6.0f (24-bit guard)

typedef float f32x4 __attribute__((ext_vector_type(4)));

// LDS-only barrier: orders LDS producer->consumer without draining vmcnt,
// so the other row's global loads stay in flight across select phases.
__device__ __forceinline__ void bar_lds() {
    asm volatile("s_waitcnt lgkmcnt(0)" ::: "memory");
    __builtin_amdgcn_sched_barrier(0);
    __builtin_amdgcn_s_barrier();
}

struct Shm {
    alignas(16) int hist[256];
    unsigned int cand[4 * SEG];
    int scnt[4];
    unsigned int wmax[4];
    unsigned int selT;
    int selNeed, selAmb;
    unsigned long long wtot64[4];
    int sel_digit, sel_kk, sel_eq, sel_flag;
};

__device__ __forceinline__ void topk_row(unsigned int (&key)[16], float* __restrict__ orow,
                                         int k, int tid, int lane, int wid, Shm& s)
{
    // ---- per-wave ballot compaction of candidates > 1.5f (+ wave max) ----
    unsigned int mx = 0u;
#pragma unroll
    for (int j = 0; j < 16; ++j) mx = key[j] > mx ? key[j] : mx;
#pragma unroll
    for (int d = 1; d < 64; d <<= 1) {
        unsigned int o = __shfl_xor(mx, d);
        mx = o > mx ? o : mx;
    }
    int base = 0;
#pragma unroll
    for (int j = 0; j < 16; ++j) {
        const bool p = key[j] > KPRE_BITS;
        const unsigned long long mask = __ballot(p);
        const int prior = __builtin_amdgcn_mbcnt_hi(
            (unsigned int)(mask >> 32),
            __builtin_amdgcn_mbcnt_lo((unsigned int)mask, 0));
        const int idx = base + prior;
        if (p && idx < SEG) s.cand[(wid << 7) + idx] = key[j] - KPRE_BITS;
        base += (int)__popcll(mask);
    }
    if (lane == 0) { s.scnt[wid] = base; s.wmax[wid] = mx; }
    bar_lds(); // B1

    const int c0 = s.scnt[0], c1 = s.scnt[1], c2 = s.scnt[2], c3 = s.scnt[3];
    const int cnt = c0 + c1 + c2 + c3;
    const bool segok = (c0 <= SEG) & (c1 <= SEG) & (c2 <= SEG) & (c3 <= SEG);
    unsigned int bmax = s.wmax[0];
    bmax = s.wmax[1] > bmax ? s.wmax[1] : bmax;
    bmax = s.wmax[2] > bmax ? s.wmax[2] : bmax;
    bmax = s.wmax[3] > bmax ? s.wmax[3] : bmax;

    unsigned int T;
    int need, amb;

    if (cnt >= k && segok && bmax < KMAX_BITS) {
        // ---- fast select: wave 0 only, 3x8-bit radix on 24-bit offset keys ----
        if (wid == 0) {
            const int sc[4] = {c0, c1, c2, c3};
            unsigned int c[8];
#pragma unroll
            for (int i = 0; i < 8; ++i) {
                const int sgi = i >> 1;
                const int off = lane + 64 * (i & 1);
                c[i] = (off < sc[sgi]) ? s.cand[(sgi << 7) + off] : 0u; // 0 = invalid
            }
            int kk = k;
            int eqv = 0;
            unsigned int prefix = 0;
#pragma unroll
            for (int p = 0; p < 3; ++p) {
                const int shift = 16 - 8 * p;
                ((int4*)s.hist)[lane] = make_int4(0, 0, 0, 0);
#pragma unroll
                for (int i = 0; i < 8; ++i) {
                    const unsigned int ci = c[i];
                    if (ci != 0u && (p == 0 || (ci >> (shift + 8)) == prefix))
                        atomicAdd(&s.hist[(ci >> shift) & 255u], 1);
                }
                const int4 h = ((const int4*)s.hist)[lane];
                const int h0 = h.x, h1 = h.y, h2 = h.z, h3 = h.w;
                const int lsum = h0 + h1 + h2 + h3;
                int suf = lsum;
#pragma unroll
                for (int d = 1; d < 64; d <<= 1) {
                    int v = __shfl_down(suf, d);
                    if (lane < 64 - d) suf += v;
                }
                const unsigned long long mm = __ballot(suf >= kk);
                const int L = 63 - __clzll(mm);
                int dig = 0, kkn = 0, eqn = 0;
                if (lane == L) {
                    int cum = suf - lsum;
                    const int hh[4] = {h0, h1, h2, h3};
#pragma unroll
                    for (int b = 3; b >= 0; --b) {
                        if (cum + hh[b] >= kk) { dig = lane * 4 + b; kkn = kk - cum; eqn = hh[b]; break; }
                        cum += hh[b];
                    }
                }
                dig = __shfl(dig, L);
                kk  = __shfl(kkn, L);
                eqv = __shfl(eqn, L);
                prefix = (prefix << 8) | (unsigned int)dig;
            }
            if (lane == 0) {
                s.selT    = prefix + KPRE_BITS;
                s.selNeed = kk;
                s.selAmb  = (eqv != kk);
            }
        }
        bar_lds(); // B2
        T    = s.selT;
        need = s.selNeed;
        amb  = s.selAmb;
    } else {
        // ---- exact fallback: full-block 4-pass histogram over all positives ----
        int kk = k;
        unsigned int prefix = 0;
        int t0 = 0;
        for (int p = 0; p < 4; ++p) {
            const int shift = 24 - 8 * p;
            s.hist[tid] = 0;
            if (tid == 0) s.sel_flag = 0;
            bar_lds();
#pragma unroll
            for (int j = 0; j < 16; ++j) {
                const unsigned int kj = key[j];
                if (kj != 0u && (p == 0 || (kj >> (shift + 8)) == prefix))
                    atomicAdd(&s.hist[(kj >> shift) & 255u], 1);
            }
            bar_lds();
            if (tid < 64) {
                const int b0 = tid * 4;
                const int h0 = s.hist[b0 + 0], h1 = s.hist[b0 + 1];
                const int h2 = s.hist[b0 + 2], h3 = s.hist[b0 + 3];
                const int lsum = h0 + h1 + h2 + h3;
                int suf = lsum;
#pragma unroll
                for (int d = 1; d < 64; d <<= 1) {
                    int v = __shfl_down(suf, d);
                    if (lane < 64 - d) suf += v;
                }
                const unsigned long long mm = __ballot(suf >= kk);
                if (mm == 0ull) {
                    if (lane == 0) s.sel_flag = 1;
                } else {
                    const int L = 63 - __clzll(mm);
                    if (lane == L) {
                        int cum = suf - lsum;
                        const int hh[4] = {h0, h1, h2, h3};
#pragma unroll
                        for (int b = 3; b >= 0; --b) {
                            if (cum + hh[b] >= kk) {
                                s.sel_digit = b0 + b; s.sel_kk = kk - cum; s.sel_eq = hh[b]; break;
                            }
                            cum += hh[b];
                        }
                    }
                }
            }
            bar_lds();
            if (s.sel_flag) { t0 = 1; break; }
            prefix = (prefix << 8) | (unsigned int)s.sel_digit;
            kk = s.sel_kk;
            bar_lds(); // protect sel_* from next pass's re-init
        }
        if (t0) { T = 0u; need = 0; amb = 1; }
        else    { T = prefix; need = kk; amb = (s.sel_eq != kk); }
    }

    if (!amb) {
        // ---- emit fast path ----
#pragma unroll
        for (int j = 0; j < 4; ++j) {
            f32x4 v;
#pragma unroll
            for (int c2 = 0; c2 < 4; ++c2) {
                const unsigned int kj = key[4 * j + c2];
                v[c2] = (kj >= T && T != 0u) ? __uint_as_float(kj) : 0.0f;
            }
            *(f32x4*)(orow + j * 1024 + tid * 4) = v;
        }
    } else {
        // ---- rare: ambiguous tie. Stable rank, column order == (j, tid, c) ----
        unsigned long long packed = 0ull;
#pragma unroll
        for (int j = 0; j < 4; ++j) {
            int e = 0;
#pragma unroll
            for (int c = 0; c < 4; ++c) e += (key[4 * j + c] == T) ? 1 : 0;
            packed |= (unsigned long long)e << (16 * j);
        }
        unsigned long long incp = packed;
#pragma unroll
        for (int d = 1; d < 64; d <<= 1) {
            unsigned long long v = __shfl_up(incp, d);
            if (lane >= d) incp += v;
        }
        if (lane == 63) s.wtot64[wid] = incp;
        bar_lds();
        unsigned long long b64 = 0ull;
        for (int w = 0; w < wid; ++w) b64 += s.wtot64[w];
        const unsigned long long exclp = b64 + incp - packed;
        const unsigned long long t64 = s.wtot64[0] + s.wtot64[1] + s.wtot64[2] + s.wtot64[3];
        int S[4];
        S[0] = 0;
        S[1] = (int)(t64 & 0xFFFFull);
        S[2] = S[1] + (int)((t64 >> 16) & 0xFFFFull);
        S[3] = S[2] + (int)((t64 >> 32) & 0xFFFFull);
#pragma unroll
        for (int j = 0; j < 4; ++j) {
            int rr = S[j] + (int)((exclp >> (16 * j)) & 0xFFFFull);
            f32x4 v;
#pragma unroll
            for (int c2 = 0; c2 < 4; ++c2) {
                const unsigned int kj = key[4 * j + c2];
                const bool eq = (kj == T);
                const bool keep = (kj > T) || (eq && rr < need);
                v[c2] = keep ? __uint_as_float(kj) : 0.0f;
                rr += eq ? 1 : 0;
            }
            *(f32x4*)(orow + j * 1024 + tid * 4) = v;
        }
    }
}

__global__ __launch_bounds__(TPB, 4)
void topk_relu_kernel(const float* __restrict__ x, const int* __restrict__ kptr,
                      float* __restrict__ out, int rows)
{
    __shared__ Shm s;

    const int tid  = threadIdx.x;
    const int lane = tid & 63;
    const int wid  = tid >> 6;

    const int rowA = blockIdx.x * 2;
    const int rowB = rowA + 1;
    if (rowA >= rows) return;

    int k = *kptr;
    if (k > ROW_LEN) k = ROW_LEN;

    // ---- issue BOTH rows' loads up front; B's stay in flight through A ----
    const float* __restrict__ xrowA = x + (size_t)rowA * ROW_LEN;
    unsigned int keyA[16];
#pragma unroll
    for (int j = 0; j < 4; ++j) {
        f32x4 v = *(const f32x4*)(xrowA + j * 1024 + tid * 4);
#pragma unroll
        for (int c = 0; c < 4; ++c)
            keyA[4 * j + c] = __float_as_uint(fmaxf(v[c], 0.0f));
    }
    const bool haveB = (rowB < rows);
    unsigned int keyB[16];
    if (haveB) {
        const float* __restrict__ xrowB = x + (size_t)rowB * ROW_LEN;
#pragma unroll
        for (int j = 0; j < 4; ++j) {
            f32x4 v = *(const f32x4*)(xrowB + j * 1024 + tid * 4);
#pragma unroll
            for (int c = 0; c < 4; ++c)
                keyB[4 * j + c] = __float_as_uint(fmaxf(v[c], 0.0f));
        }
    }

    topk_row(keyA, out + (size_t)rowA * ROW_LEN, k, tid, lane, wid, s);
    if (haveB) {
        bar_lds(); // LDS reuse fence between rows
        topk_row(keyB, out + (size_t)rowB * ROW_LEN, k, tid, lane, wid, s);
    }
}

extern "C" void kernel_launch(void* const* d_in, const int* in_sizes, int n_in,
                              void* d_out, int out_size, void* d_ws, size_t ws_size,
                              hipStream_t stream)
{
    const float* x    = (const float*)d_in[0];
    const int*   kptr = (const int*)d_in[1];
    float*       out  = (float*)d_out;
    const int rows = in_sizes[0] / ROW_LEN;
    const int nb = (rows + 1) / 2;
    topk_relu_kernel<<<nb, TPB, 0, stream>>>(x, kptr, out, rows);
}

// Round 14
// 101.724 us; speedup vs baseline: 1.0527x; 1.0527x over previous
//
#include <hip/hip_runtime.h>

// TopKActivation: out = relu(x) masked to the row-wise top-k of relu(x).
// [16384 x 4096] fp32, k=64. One 256-thread block per row, interleaved
// coalesced layout (thread t, chunk j -> cols j*1024 + 4t..+3).
//
// LESSON LEDGER:
//  R3:  persistent+prefetch+bar_lds -> 214us. CONFOUNDED: had NT stores.
//  R4:  launch_bounds(256,8)+NT stores -> 302us. MISATTRIBUTED to VGPR spill;
//       VGPR_Count was 28 (no spill). NT stores were the poison (see R5).
//  R5:  NT stores (lb 4) -> 523MB writes: partial-line HBM write amp. POISON.
//  R6:  plain stores -> 127.5us (VGPR 28, clean writes).
//  R7:  coalesced interleaved layout -> 100.9us (was 4x transactions).
//  R8:  redundant all-wave select -> 112.5us (4x shared-pipe LDS traffic).
//  R9:  ballot compaction + tie fast-path -> 100.1us.
//  R11: zero-barrier wave-per-row -> 114.4us (VGPR pressure, serial ballots).
//  R12: 3-pass offset radix, 2 barriers -> 101.2us (select isn't the gap).
//  R13: 2 rows/block + LDS-only barriers -> 107.1us (overlap falsified 3x).
//  R14 (this): R12 + launch_bounds(256,8) WITHOUT NT stores (never tested).
//       Mechanism: 4 resident blocks/CU stay phase-correlated (equal-length
//       blocks dispatched together) -> select windows coincide -> ~85% memory
//       duty cycle. 8 blocks/CU de-correlates phases + deepens load queue.
//       Spill tripwire: WRITE_SIZE >> 268MB means the 64-VGPR cap bit; revert.
//
// Select: candidates > 1.5f ballot-compacted (as key-1.5bits, 24-bit) into 4
// per-wave 128-slot segments; wave 0 runs 3x8-bit MSB radix. Exact full-block
// fallback if any segment overflows, cnt<k, or any element >= 6.0. Tie
// ambiguity decided in-select (final-pass bin count == multiplicity of T);
// stable ranks (lowest column first, == XLA top_k) only on ambiguous rows.

constexpr int ROW_LEN = 4096;
constexpr int TPB     = 256;
constexpr int SEG     = 128;   // per-wave candidate capacity
constexpr unsigned int KPRE_BITS = 0x3FC00000u; // bits of 1.5f
constexpr unsigned int KMAX_BITS = 0x40C00000u; // bits of 6.0f (24-bit guard)

typedef float f32x4 __attribute__((ext_vector_type(4)));

__global__ __launch_bounds__(TPB, 8)
void topk_relu_kernel(const float* __restrict__ x, const int* __restrict__ kptr,
                      float* __restrict__ out, int rows)
{
    __shared__ alignas(16) int hist[256];
    __shared__ unsigned int cand[4 * SEG];  // 4 segments of 128 (24-bit offset keys)
    __shared__ int scnt[4];
    __shared__ unsigned int wmax[4];
    __shared__ unsigned int selT;
    __shared__ int selNeed, selAmb;
    __shared__ unsigned long long wtot64[4];
    __shared__ int sel_digit, sel_kk, sel_eq, sel_flag;

    const int row = blockIdx.x;
    if (row >= rows) return;
    const int tid  = threadIdx.x;
    const int lane = tid & 63;
    const int wid  = tid >> 6;

    int k = *kptr;
    if (k > ROW_LEN) k = ROW_LEN;

    // ---- load row, interleaved coalesced: thread t chunk j -> cols j*1024+4t..+3 ----
    const float* __restrict__ xrow = x + (size_t)row * ROW_LEN;
    unsigned int key[16];
#pragma unroll
    for (int j = 0; j < 4; ++j) {
        f32x4 v = *(const f32x4*)(xrow + j * 1024 + tid * 4);
#pragma unroll
        for (int c = 0; c < 4; ++c)
            key[4 * j + c] = __float_as_uint(fmaxf(v[c], 0.0f));
    }

    // ---- per-wave ballot compaction of candidates > 1.5f (stored as key-1.5bits)
    //      + wave max (for the 24-bit guard) ----
    unsigned int mx = 0u;
#pragma unroll
    for (int j = 0; j < 16; ++j) mx = key[j] > mx ? key[j] : mx;
#pragma unroll
    for (int d = 1; d < 64; d <<= 1) {
        unsigned int o = __shfl_xor(mx, d);
        mx = o > mx ? o : mx;
    }
    int base = 0;
#pragma unroll
    for (int j = 0; j < 16; ++j) {
        const bool p = key[j] > KPRE_BITS;
        const unsigned long long mask = __ballot(p);
        const int prior = __builtin_amdgcn_mbcnt_hi(
            (unsigned int)(mask >> 32),
            __builtin_amdgcn_mbcnt_lo((unsigned int)mask, 0));
        const int idx = base + prior;
        if (p && idx < SEG) cand[(wid << 7) + idx] = key[j] - KPRE_BITS;
        base += (int)__popcll(mask);
    }
    if (lane == 0) { scnt[wid] = base; wmax[wid] = mx; }
    __syncthreads(); // B1: segments + counts + maxes ready

    const int c0 = scnt[0], c1 = scnt[1], c2 = scnt[2], c3 = scnt[3];
    const int cnt = c0 + c1 + c2 + c3;
    const bool segok = (c0 <= SEG) & (c1 <= SEG) & (c2 <= SEG) & (c3 <= SEG);
    unsigned int bmax = wmax[0];
    bmax = wmax[1] > bmax ? wmax[1] : bmax;
    bmax = wmax[2] > bmax ? wmax[2] : bmax;
    bmax = wmax[3] > bmax ? wmax[3] : bmax;

    unsigned int T;
    int need, amb;

    if (cnt >= k && segok && bmax < KMAX_BITS) {
        // ---- fast select: wave 0 only, 3x8-bit radix on 24-bit offset keys ----
        if (wid == 0) {
            const int sc[4] = {c0, c1, c2, c3};
            unsigned int c[8];
#pragma unroll
            for (int i = 0; i < 8; ++i) {
                const int s   = i >> 1;
                const int off = lane + 64 * (i & 1);
                c[i] = (off < sc[s]) ? cand[(s << 7) + off] : 0u; // 0 = invalid (cands >= 1)
            }
            int kk = k;
            int eqv = 0;
            unsigned int prefix = 0;
#pragma unroll
            for (int p = 0; p < 3; ++p) {
                const int shift = 16 - 8 * p;
                ((int4*)hist)[lane] = make_int4(0, 0, 0, 0);
#pragma unroll
                for (int i = 0; i < 8; ++i) {
                    const unsigned int ci = c[i];
                    if (ci != 0u && (p == 0 || (ci >> (shift + 8)) == prefix))
                        atomicAdd(&hist[(ci >> shift) & 255u], 1);
                }
                const int4 h = ((const int4*)hist)[lane];
                const int h0 = h.x, h1 = h.y, h2 = h.z, h3 = h.w;
                const int lsum = h0 + h1 + h2 + h3;
                int suf = lsum; // inclusive suffix sum across lanes
#pragma unroll
                for (int d = 1; d < 64; d <<= 1) {
                    int v = __shfl_down(suf, d);
                    if (lane < 64 - d) suf += v;
                }
                const unsigned long long mm = __ballot(suf >= kk); // nonzero: cnt>=kk
                const int L = 63 - __clzll(mm);
                int dig = 0, kkn = 0, eqn = 0;
                if (lane == L) {
                    int cum = suf - lsum;
                    const int hh[4] = {h0, h1, h2, h3};
#pragma unroll
                    for (int b = 3; b >= 0; --b) {
                        if (cum + hh[b] >= kk) { dig = lane * 4 + b; kkn = kk - cum; eqn = hh[b]; break; }
                        cum += hh[b];
                    }
                }
                dig = __shfl(dig, L);
                kk  = __shfl(kkn, L);
                eqv = __shfl(eqn, L);
                prefix = (prefix << 8) | (unsigned int)dig;
            }
            if (lane == 0) {
                selT    = prefix + KPRE_BITS; // back to full float bits
                selNeed = kk;
                selAmb  = (eqv != kk); // final-pass bin count == multiplicity of T
            }
        }
        __syncthreads(); // B2: T/need/amb ready
        T    = selT;
        need = selNeed;
        amb  = selAmb;
    } else {
        // ---- exact fallback: full-block 4-pass histogram over all positives ----
        int kk = k;
        unsigned int prefix = 0;
        int t0 = 0;
        for (int p = 0; p < 4; ++p) {
            const int shift = 24 - 8 * p;
            hist[tid] = 0;
            if (tid == 0) sel_flag = 0;
            __syncthreads();
#pragma unroll
            for (int j = 0; j < 16; ++j) {
                const unsigned int kj = key[j];
                if (kj != 0u && (p == 0 || (kj >> (shift + 8)) == prefix))
                    atomicAdd(&hist[(kj >> shift) & 255u], 1);
            }
            __syncthreads();
            if (tid < 64) {
                const int b0 = tid * 4;
                const int h0 = hist[b0 + 0], h1 = hist[b0 + 1];
                const int h2 = hist[b0 + 2], h3 = hist[b0 + 3];
                const int lsum = h0 + h1 + h2 + h3;
                int suf = lsum;
#pragma unroll
                for (int d = 1; d < 64; d <<= 1) {
                    int v = __shfl_down(suf, d);
                    if (lane < 64 - d) suf += v;
                }
                const unsigned long long mm = __ballot(suf >= kk);
                if (mm == 0ull) {
                    if (lane == 0) sel_flag = 1;
                } else {
                    const int L = 63 - __clzll(mm);
                    if (lane == L) {
                        int cum = suf - lsum;
                        const int hh[4] = {h0, h1, h2, h3};
#pragma unroll
                        for (int b = 3; b >= 0; --b) {
                            if (cum + hh[b] >= kk) {
                                sel_digit = b0 + b; sel_kk = kk - cum; sel_eq = hh[b]; break;
                            }
                            cum += hh[b];
                        }
                    }
                }
            }
            __syncthreads();
            if (sel_flag) { t0 = 1; break; }
            prefix = (prefix << 8) | (unsigned int)sel_digit;
            kk = sel_kk;
            __syncthreads(); // protect sel_* from next pass's re-init
        }
        if (t0) { T = 0u; need = 0; amb = 1; } // rank path yields keep = (kj > 0)
        else    { T = prefix; need = kk; amb = (sel_eq != kk); }
    }

    float* __restrict__ orow = out + (size_t)row * ROW_LEN;

    if (!amb) {
        // ---- emit fast path: all ==T kept, no rank bookkeeping ----
#pragma unroll
        for (int j = 0; j < 4; ++j) {
            f32x4 v;
#pragma unroll
            for (int c2 = 0; c2 < 4; ++c2) {
                const unsigned int kj = key[4 * j + c2];
                v[c2] = (kj >= T && T != 0u) ? __uint_as_float(kj) : 0.0f;
            }
            *(f32x4*)(orow + j * 1024 + tid * 4) = v;
        }
    } else {
        // ---- rare: ambiguous tie at T (or t0 fallback). Stable rank in column
        //      order == lexicographic (j, tid, c). Packed 4x16-bit block scan. ----
        unsigned long long packed = 0ull;
#pragma unroll
        for (int j = 0; j < 4; ++j) {
            int e = 0;
#pragma unroll
            for (int c = 0; c < 4; ++c) e += (key[4 * j + c] == T) ? 1 : 0;
            packed |= (unsigned long long)e << (16 * j);
        }
        unsigned long long incp = packed;
#pragma unroll
        for (int d = 1; d < 64; d <<= 1) {
            unsigned long long v = __shfl_up(incp, d);
            if (lane >= d) incp += v;
        }
        if (lane == 63) wtot64[wid] = incp;
        __syncthreads(); // rare path only
        unsigned long long b64 = 0ull;
        for (int w = 0; w < wid; ++w) b64 += wtot64[w];
        const unsigned long long exclp = b64 + incp - packed;
        const unsigned long long t64 = wtot64[0] + wtot64[1] + wtot64[2] + wtot64[3];
        int S[4];
        S[0] = 0;
        S[1] = (int)(t64 & 0xFFFFull);
        S[2] = S[1] + (int)((t64 >> 16) & 0xFFFFull);
        S[3] = S[2] + (int)((t64 >> 32) & 0xFFFFull);
#pragma unroll
        for (int j = 0; j < 4; ++j) {
            int rr = S[j] + (int)((exclp >> (16 * j)) & 0xFFFFull);
            f32x4 v;
#pragma unroll
            for (int c2 = 0; c2 < 4; ++c2) {
                const unsigned int kj = key[4 * j + c2];
                const bool eq = (kj == T);
                const bool keep = (kj > T) || (eq && rr < need);
                v[c2] = keep ? __uint_as_float(kj) : 0.0f;
                rr += eq ? 1 : 0;
            }
            *(f32x4*)(orow + j * 1024 + tid * 4) = v;
        }
    }
}

extern "C" void kernel_launch(void* const* d_in, const int* in_sizes, int n_in,
                              void* d_out, int out_size, void* d_ws, size_t ws_size,
                              hipStream_t stream)
{
    const float* x    = (const float*)d_in[0];
    const int*   kptr = (const int*)d_in[1];
    float*       out  = (float*)d_out;
    const int rows = in_sizes[0] / ROW_LEN;
    topk_relu_kernel<<<rows, TPB, 0, stream>>>(x, kptr, out, rows);
}